// Round 1
// baseline (644.958 us; speedup 1.0000x reference)
//
#include <hip/hip_runtime.h>
#include <hip/hip_bf16.h>
#include <math.h>

#define NEG_SLOPE 0.2f

// ---------------- init ----------------
__global__ void init_kernel(int* deg, int* cursor, float* pooled, int N, int P) {
    int i = blockIdx.x * blockDim.x + threadIdx.x;
    if (i < N) { deg[i] = 0; cursor[i] = 0; }
    if (i < P) pooled[i] = 0.f;
}

// ---------------- CSR build ----------------
__global__ void count_kernel(const int* __restrict__ edst, int E, int N, int* deg) {
    int i = blockIdx.x * blockDim.x + threadIdx.x;
    int total = E + N;
    if (i >= total) return;
    int dn = (i < E) ? edst[i] : (i - E);
    atomicAdd(&deg[dn], 1);
}

__global__ void scan_kernel(const int* __restrict__ deg, int N, int* __restrict__ offsets) {
    __shared__ int part[257];
    int tid = threadIdx.x;
    int chunk = (N + 255) / 256;
    int begin = tid * chunk;
    int fin = begin + chunk; if (fin > N) fin = N; if (begin > N) begin = N;
    int sum = 0;
    for (int i = begin; i < fin; ++i) sum += deg[i];
    part[tid] = sum;
    __syncthreads();
    if (tid == 0) {
        int acc = 0;
        for (int t = 0; t < 256; ++t) { int v = part[t]; part[t] = acc; acc += v; }
        part[256] = acc;
    }
    __syncthreads();
    int acc = part[tid];
    for (int i = begin; i < fin; ++i) { offsets[i] = acc; acc += deg[i]; }
    if (tid == 255) offsets[N] = part[256];
}

__global__ void scatter_kernel(const int* __restrict__ edst, int E, int N,
                               const int* __restrict__ offsets, int* cursor, int* eids) {
    int i = blockIdx.x * blockDim.x + threadIdx.x;
    int total = E + N;
    if (i >= total) return;
    int dn = (i < E) ? edst[i] : (i - E);
    int pos = atomicAdd(&cursor[dn], 1);
    eids[offsets[dn] + pos] = i;
}

// ---------------- GEMM: C[N,F] = A[N,K] @ B[K,F], fp32, 64x64x16 tiles ----------------
__global__ __launch_bounds__(256) void gemm_kernel(const float* __restrict__ A,
                                                   const float* __restrict__ B,
                                                   float* __restrict__ C,
                                                   int N, int K, int F) {
    __shared__ float As[16][68]; // As[k][m]
    __shared__ float Bs[16][68]; // Bs[k][n]
    int tid = threadIdx.x;
    int bm = blockIdx.x * 64;
    int bn = blockIdx.y * 64;
    int tx = tid % 16, ty = tid / 16;
    int arow = tid / 4;        // 0..63
    int akq  = (tid % 4) * 4;  // 0,4,8,12
    int brow = tid / 16;       // 0..15
    int bcq  = (tid % 16) * 4; // 0..60
    float acc[4][4] = {};
    for (int k0 = 0; k0 < K; k0 += 16) {
        float4 av = make_float4(0.f, 0.f, 0.f, 0.f);
        int gr = bm + arow;
        if (gr < N) av = *reinterpret_cast<const float4*>(A + (size_t)gr * K + k0 + akq);
        As[akq + 0][arow] = av.x;
        As[akq + 1][arow] = av.y;
        As[akq + 2][arow] = av.z;
        As[akq + 3][arow] = av.w;
        float4 bv = *reinterpret_cast<const float4*>(B + (size_t)(k0 + brow) * F + bn + bcq);
        *reinterpret_cast<float4*>(&Bs[brow][bcq]) = bv;
        __syncthreads();
#pragma unroll
        for (int kk = 0; kk < 16; ++kk) {
            float ar[4], br[4];
#pragma unroll
            for (int r = 0; r < 4; ++r) ar[r] = As[kk][ty * 4 + r];
#pragma unroll
            for (int c = 0; c < 4; ++c) br[c] = Bs[kk][tx * 4 + c];
#pragma unroll
            for (int r = 0; r < 4; ++r)
#pragma unroll
                for (int c = 0; c < 4; ++c)
                    acc[r][c] += ar[r] * br[c];
        }
        __syncthreads();
    }
#pragma unroll
    for (int r = 0; r < 4; ++r) {
        int gr = bm + ty * 4 + r;
        if (gr >= N) continue;
        float4 v = make_float4(acc[r][0], acc[r][1], acc[r][2], acc[r][3]);
        *reinterpret_cast<float4*>(C + (size_t)gr * F + bn + tx * 4) = v;
    }
}

// ---------------- attention scalars: s[n]=h[n]·a_s, d[n]=h[n]·a_d ----------------
__global__ void sd_kernel(const float* __restrict__ h, const float* __restrict__ a_s,
                          const float* __restrict__ a_d, int N, int F,
                          float* __restrict__ s, float* __restrict__ d) {
    int wave = (blockIdx.x * blockDim.x + threadIdx.x) >> 6;
    int lane = threadIdx.x & 63;
    if (wave >= N) return;
    const float* hrow = h + (size_t)wave * F;
    float ss = 0.f, dd = 0.f;
    for (int f = lane; f < F; f += 64) {
        float hv = hrow[f];
        ss += hv * a_s[f];
        dd += hv * a_d[f];
    }
    for (int off = 32; off; off >>= 1) {
        ss += __shfl_down(ss, off);
        dd += __shfl_down(dd, off);
    }
    if (lane == 0) { s[wave] = ss; d[wave] = dd; }
}

// ---------------- per-edge logits ----------------
__global__ void edge_e_kernel(const float* __restrict__ s, const float* __restrict__ d,
                              const int* __restrict__ esrc, const int* __restrict__ edst,
                              int E, int N, float* __restrict__ evals) {
    int i = blockIdx.x * blockDim.x + threadIdx.x;
    int total = E + N;
    if (i >= total) return;
    int sn, dn;
    if (i < E) { sn = esrc[i]; dn = edst[i]; } else { sn = i - E; dn = i - E; }
    float v = s[sn] + d[dn];
    evals[i] = (v >= 0.f) ? v : NEG_SLOPE * v;
}

// ---------------- per-node softmax + aggregate + bias + relu ----------------
__global__ __launch_bounds__(256) void agg_kernel(const float* __restrict__ h,
                                                  const float* __restrict__ evals,
                                                  const int* __restrict__ offsets,
                                                  const int* __restrict__ eids,
                                                  const int* __restrict__ esrc,
                                                  int E, int F,
                                                  const float* __restrict__ bias,
                                                  float* __restrict__ out) {
    int n = blockIdx.x;
    int start = offsets[n], end = offsets[n + 1];
    int tid = threadIdx.x;
    __shared__ float red[256];
    // max
    float lmax = -INFINITY;
    for (int j = start + tid; j < end; j += 256) lmax = fmaxf(lmax, evals[eids[j]]);
    red[tid] = lmax;
    __syncthreads();
    for (int sft = 128; sft > 0; sft >>= 1) {
        if (tid < sft) red[tid] = fmaxf(red[tid], red[tid + sft]);
        __syncthreads();
    }
    float m = red[0];
    __syncthreads();
    // denom
    float lsum = 0.f;
    for (int j = start + tid; j < end; j += 256) lsum += expf(evals[eids[j]] - m);
    red[tid] = lsum;
    __syncthreads();
    for (int sft = 128; sft > 0; sft >>= 1) {
        if (tid < sft) red[tid] += red[tid + sft];
        __syncthreads();
    }
    float inv_denom = 1.f / red[0];
    // aggregate
    float acc[4] = {0.f, 0.f, 0.f, 0.f};
    int nf = (F + 255) / 256;
    for (int j = start; j < end; ++j) {
        int eid = eids[j];
        int sn = (eid < E) ? esrc[eid] : (eid - E);
        float alpha = expf(evals[eid] - m) * inv_denom;
        const float* hrow = h + (size_t)sn * F;
        for (int q = 0; q < nf; ++q) {
            int f = q * 256 + tid;
            if (f < F) acc[q] += alpha * hrow[f];
        }
    }
    float* orow = out + (size_t)n * F;
    for (int q = 0; q < nf; ++q) {
        int f = q * 256 + tid;
        if (f < F) orow[f] = fmaxf(acc[q] + bias[f], 0.f);
    }
}

// ---------------- global max pool (values >= 0 after relu) ----------------
__global__ void pool_kernel(const float* __restrict__ h, int N, float* __restrict__ pooled) {
    int b = blockIdx.x, tid = threadIdx.x;
    int chunk = (N + gridDim.x - 1) / gridDim.x;
    int r0 = b * chunk, r1 = r0 + chunk; if (r1 > N) r1 = N;
    float mx[4] = {0.f, 0.f, 0.f, 0.f};
    for (int r = r0; r < r1; ++r) {
        const float* row = h + (size_t)r * 1024;
#pragma unroll
        for (int q = 0; q < 4; ++q) mx[q] = fmaxf(mx[q], row[q * 256 + tid]);
    }
#pragma unroll
    for (int q = 0; q < 4; ++q)
        atomicMax((int*)&pooled[q * 256 + tid], __float_as_int(mx[q]));
}

// ---------------- dense head ----------------
__global__ void head1_kernel(const float* __restrict__ pooled, const float* __restrict__ lw1,
                             const float* __restrict__ lb1, float* __restrict__ z1) {
    int j = blockIdx.x * 256 + threadIdx.x; // 512 outputs
    float acc = lb1[j];
    for (int k = 0; k < 1024; ++k) acc += pooled[k] * lw1[k * 512 + j];
    z1[j] = fmaxf(acc, 0.f);
}

__global__ void head2_kernel(const float* __restrict__ z1, const float* __restrict__ lw2,
                             const float* __restrict__ lb2, float* __restrict__ out) {
    __shared__ float z2[10];
    int tid = threadIdx.x;
    if (tid < 10) {
        float acc = lb2[tid];
        for (int k = 0; k < 512; ++k) acc += z1[k] * lw2[k * 10 + tid];
        z2[tid] = acc;
    }
    __syncthreads();
    if (tid == 0) {
        float m = z2[0];
        for (int j = 1; j < 10; ++j) m = fmaxf(m, z2[j]);
        float ssum = 0.f;
        for (int j = 0; j < 10; ++j) ssum += expf(z2[j] - m);
        float lse = m + logf(ssum);
        for (int j = 0; j < 10; ++j) out[j] = z2[j] - lse;
    }
}

extern "C" void kernel_launch(void* const* d_in, const int* in_sizes, int n_in,
                              void* d_out, int out_size, void* d_ws, size_t ws_size,
                              hipStream_t stream) {
    const float* x   = (const float*)d_in[0];
    const int* ei    = (const int*)d_in[1];
    const float* W1  = (const float*)d_in[3];
    const float* as1 = (const float*)d_in[4];
    const float* ad1 = (const float*)d_in[5];
    const float* b1  = (const float*)d_in[6];
    const float* W2  = (const float*)d_in[7];
    const float* as2 = (const float*)d_in[8];
    const float* ad2 = (const float*)d_in[9];
    const float* b2  = (const float*)d_in[10];
    const float* W3  = (const float*)d_in[11];
    const float* as3 = (const float*)d_in[12];
    const float* ad3 = (const float*)d_in[13];
    const float* b3  = (const float*)d_in[14];
    const float* lw1 = (const float*)d_in[15];
    const float* lb1 = (const float*)d_in[16];
    const float* lw2 = (const float*)d_in[17];
    const float* lb2 = (const float*)d_in[18];
    float* out = (float*)d_out;

    const int N = in_sizes[0] / 128;
    const int E = in_sizes[1] / 2;
    const int total = E + N;
    const int* esrc = ei;
    const int* edst = ei + E;

    float* ws = (float*)d_ws;
    float* hbuf   = ws;                    // N*1024
    float* abuf   = hbuf + (size_t)N * 1024;
    float* sbuf   = abuf + (size_t)N * 1024;
    float* dbuf   = sbuf + N;
    float* evals  = dbuf + N;              // total
    float* pooled = evals + total;         // 1024
    float* z1     = pooled + 1024;         // 512
    int* deg     = (int*)(z1 + 512);       // N
    int* cursor  = deg + N;                // N
    int* offsets = cursor + N;             // N+1
    int* eids    = offsets + N + 1;        // total

    const int TPB = 256;
    int gN = (N + TPB - 1) / TPB;
    int gE = (total + TPB - 1) / TPB;

    // init + CSR build (once; depends only on edge_index)
    init_kernel<<<gN, TPB, 0, stream>>>(deg, cursor, pooled, N, 1024);
    count_kernel<<<gE, TPB, 0, stream>>>(edst, E, N, deg);
    scan_kernel<<<1, TPB, 0, stream>>>(deg, N, offsets);
    scatter_kernel<<<gE, TPB, 0, stream>>>(edst, E, N, offsets, cursor, eids);

    int gRows = (N + 63) / 64;
    int gSD = (N * 64 + TPB - 1) / TPB;

    // ---- layer 1: 128 -> 64 ----
    {
        dim3 grid(gRows, 64 / 64);
        gemm_kernel<<<grid, TPB, 0, stream>>>(x, W1, hbuf, N, 128, 64);
        sd_kernel<<<gSD, TPB, 0, stream>>>(hbuf, as1, ad1, N, 64, sbuf, dbuf);
        edge_e_kernel<<<gE, TPB, 0, stream>>>(sbuf, dbuf, esrc, edst, E, N, evals);
        agg_kernel<<<N, TPB, 0, stream>>>(hbuf, evals, offsets, eids, esrc, E, 64, b1, abuf);
    }
    // ---- layer 2: 64 -> 256 ----
    {
        dim3 grid(gRows, 256 / 64);
        gemm_kernel<<<grid, TPB, 0, stream>>>(abuf, W2, hbuf, N, 64, 256);
        sd_kernel<<<gSD, TPB, 0, stream>>>(hbuf, as2, ad2, N, 256, sbuf, dbuf);
        edge_e_kernel<<<gE, TPB, 0, stream>>>(sbuf, dbuf, esrc, edst, E, N, evals);
        agg_kernel<<<N, TPB, 0, stream>>>(hbuf, evals, offsets, eids, esrc, E, 256, b2, abuf);
    }
    // ---- layer 3: 256 -> 1024 ----
    {
        dim3 grid(gRows, 1024 / 64);
        gemm_kernel<<<grid, TPB, 0, stream>>>(abuf, W3, hbuf, N, 256, 1024);
        sd_kernel<<<gSD, TPB, 0, stream>>>(hbuf, as3, ad3, N, 1024, sbuf, dbuf);
        edge_e_kernel<<<gE, TPB, 0, stream>>>(sbuf, dbuf, esrc, edst, E, N, evals);
        agg_kernel<<<N, TPB, 0, stream>>>(hbuf, evals, offsets, eids, esrc, E, 1024, b3, abuf);
    }
    // ---- pool + head ----
    pool_kernel<<<64, TPB, 0, stream>>>(abuf, N, pooled);
    head1_kernel<<<2, TPB, 0, stream>>>(pooled, lw1, lb1, z1);
    head2_kernel<<<1, 64, 0, stream>>>(z1, lw2, lb2, out);
}

// Round 2
// 400.409 us; speedup vs baseline: 1.6107x; 1.6107x over previous
//
#include <hip/hip_runtime.h>
#include <hip/hip_bf16.h>
#include <math.h>

#define NEG_SLOPE 0.2f

__device__ __forceinline__ float bfu2f(unsigned short u) {
    return __uint_as_float(((unsigned)u) << 16);
}

// ---------------- init ----------------
__global__ void init_kernel(int* deg, int* cursor, float* pooled, int N, int P) {
    int i = blockIdx.x * blockDim.x + threadIdx.x;
    if (i < N) { deg[i] = 0; cursor[i] = 0; }
    if (i < P) pooled[i] = 0.f;
}

// ---------------- CSR build ----------------
__global__ void count_kernel(const int* __restrict__ edst, int E, int N, int* deg) {
    int i = blockIdx.x * blockDim.x + threadIdx.x;
    int total = E + N;
    if (i >= total) return;
    int dn = (i < E) ? edst[i] : (i - E);
    atomicAdd(&deg[dn], 1);
}

__global__ void scan_kernel(const int* __restrict__ deg, int N, int* __restrict__ offsets) {
    __shared__ int part[257];
    int tid = threadIdx.x;
    int chunk = (N + 255) / 256;
    int begin = tid * chunk;
    int fin = begin + chunk; if (fin > N) fin = N; if (begin > N) begin = N;
    int sum = 0;
    for (int i = begin; i < fin; ++i) sum += deg[i];
    part[tid] = sum;
    __syncthreads();
    if (tid == 0) {
        int acc = 0;
        for (int t = 0; t < 256; ++t) { int v = part[t]; part[t] = acc; acc += v; }
        part[256] = acc;
    }
    __syncthreads();
    int acc = part[tid];
    for (int i = begin; i < fin; ++i) { offsets[i] = acc; acc += deg[i]; }
    if (tid == 255) offsets[N] = part[256];
}

__global__ void scatter_kernel(const int* __restrict__ edst, int E, int N,
                               const int* __restrict__ offsets, int* cursor, int* eids) {
    int i = blockIdx.x * blockDim.x + threadIdx.x;
    int total = E + N;
    if (i >= total) return;
    int dn = (i < E) ? edst[i] : (i - E);
    int pos = atomicAdd(&cursor[dn], 1);
    eids[offsets[dn] + pos] = i;
}

// per-slot src/dst node ids in CSR order (computed once per call)
__global__ void csr_meta_kernel(const int* __restrict__ eids, const int* __restrict__ esrc,
                                const int* __restrict__ edst, int E, int total,
                                int* __restrict__ srcg, int* __restrict__ dstg) {
    int j = blockIdx.x * blockDim.x + threadIdx.x;
    if (j >= total) return;
    int eid = eids[j];
    int sn, dn;
    if (eid < E) { sn = esrc[eid]; dn = edst[eid]; } else { sn = eid - E; dn = eid - E; }
    srcg[j] = sn;
    dstg[j] = dn;
}

// ---------------- GEMM: C[N,F] = A[N,K] @ B[K,F], fp32 math, bf16 output ----------------
__global__ __launch_bounds__(256) void gemm_kernel(const float* __restrict__ A,
                                                   const float* __restrict__ B,
                                                   __hip_bfloat16* __restrict__ C,
                                                   int N, int K, int F) {
    __shared__ float As[16][68]; // As[k][m]
    __shared__ float Bs[16][68]; // Bs[k][n]
    int tid = threadIdx.x;
    int bm = blockIdx.x * 64;
    int bn = blockIdx.y * 64;
    int tx = tid % 16, ty = tid / 16;
    int arow = tid / 4;
    int akq  = (tid % 4) * 4;
    int brow = tid / 16;
    int bcq  = (tid % 16) * 4;
    float acc[4][4] = {};
    for (int k0 = 0; k0 < K; k0 += 16) {
        float4 av = make_float4(0.f, 0.f, 0.f, 0.f);
        int gr = bm + arow;
        if (gr < N) av = *reinterpret_cast<const float4*>(A + (size_t)gr * K + k0 + akq);
        As[akq + 0][arow] = av.x;
        As[akq + 1][arow] = av.y;
        As[akq + 2][arow] = av.z;
        As[akq + 3][arow] = av.w;
        float4 bv = *reinterpret_cast<const float4*>(B + (size_t)(k0 + brow) * F + bn + bcq);
        *reinterpret_cast<float4*>(&Bs[brow][bcq]) = bv;
        __syncthreads();
#pragma unroll
        for (int kk = 0; kk < 16; ++kk) {
            float ar[4], br[4];
#pragma unroll
            for (int r = 0; r < 4; ++r) ar[r] = As[kk][ty * 4 + r];
#pragma unroll
            for (int c = 0; c < 4; ++c) br[c] = Bs[kk][tx * 4 + c];
#pragma unroll
            for (int r = 0; r < 4; ++r)
#pragma unroll
                for (int c = 0; c < 4; ++c)
                    acc[r][c] += ar[r] * br[c];
        }
        __syncthreads();
    }
#pragma unroll
    for (int r = 0; r < 4; ++r) {
        int gr = bm + ty * 4 + r;
        if (gr >= N) continue;
        ushort4 v;
        v.x = __bfloat16_as_ushort(__float2bfloat16(acc[r][0]));
        v.y = __bfloat16_as_ushort(__float2bfloat16(acc[r][1]));
        v.z = __bfloat16_as_ushort(__float2bfloat16(acc[r][2]));
        v.w = __bfloat16_as_ushort(__float2bfloat16(acc[r][3]));
        *reinterpret_cast<ushort4*>((unsigned short*)C + (size_t)gr * F + bn + tx * 4) = v;
    }
}

// ---------------- attention scalars from bf16 h ----------------
__global__ void sd_kernel(const __hip_bfloat16* __restrict__ h, const float* __restrict__ a_s,
                          const float* __restrict__ a_d, int N, int F,
                          float* __restrict__ s, float* __restrict__ d) {
    int wave = (blockIdx.x * blockDim.x + threadIdx.x) >> 6;
    int lane = threadIdx.x & 63;
    if (wave >= N) return;
    const unsigned short* hrow = (const unsigned short*)h + (size_t)wave * F;
    float ss = 0.f, dd = 0.f;
    for (int f = lane * 4; f < F; f += 256) {
        ushort4 u = *reinterpret_cast<const ushort4*>(hrow + f);
        float4 av = *reinterpret_cast<const float4*>(a_s + f);
        float4 dv = *reinterpret_cast<const float4*>(a_d + f);
        float h0 = bfu2f(u.x), h1 = bfu2f(u.y), h2 = bfu2f(u.z), h3 = bfu2f(u.w);
        ss += h0 * av.x + h1 * av.y + h2 * av.z + h3 * av.w;
        dd += h0 * dv.x + h1 * dv.y + h2 * dv.z + h3 * dv.w;
    }
    for (int off = 32; off; off >>= 1) {
        ss += __shfl_down(ss, off);
        dd += __shfl_down(dd, off);
    }
    if (lane == 0) { s[wave] = ss; d[wave] = dd; }
}

// ---------------- per-slot logits (CSR order) ----------------
__global__ void edge_kernel(const float* __restrict__ s, const float* __restrict__ d,
                            const int* __restrict__ srcg, const int* __restrict__ dstg,
                            int total, float* __restrict__ eg) {
    int j = blockIdx.x * blockDim.x + threadIdx.x;
    if (j >= total) return;
    float v = s[srcg[j]] + d[dstg[j]];
    eg[j] = (v >= 0.f) ? v : NEG_SLOPE * v;
}

// ---------------- wave-per-node: softmax over slots -> alpha (CSR order) ----------------
__global__ void mden_alpha_kernel(const float* __restrict__ eg, const int* __restrict__ offsets,
                                  int N, float* __restrict__ ag) {
    int n = (blockIdx.x * blockDim.x + threadIdx.x) >> 6;
    int lane = threadIdx.x & 63;
    if (n >= N) return;
    int start = offsets[n], end = offsets[n + 1];
    float lmax = -INFINITY;
    for (int j = start + lane; j < end; j += 64) lmax = fmaxf(lmax, eg[j]);
    for (int off = 32; off; off >>= 1) lmax = fmaxf(lmax, __shfl_xor(lmax, off));
    float ls = 0.f;
    for (int j = start + lane; j < end; j += 64) ls += expf(eg[j] - lmax);
    for (int off = 32; off; off >>= 1) ls += __shfl_xor(ls, off);
    float inv = 1.f / ls;
    for (int j = start + lane; j < end; j += 64) ag[j] = expf(eg[j] - lmax) * inv;
}

// ---------------- SpMM: out[n,f] = relu(sum_j alpha_j * h[src_j, f] + bias[f]) ----------------
template <int VPT>
__global__ void spmm_kernel(const __hip_bfloat16* __restrict__ h, const float* __restrict__ ag,
                            const int* __restrict__ srcg, const int* __restrict__ offsets,
                            int F, const float* __restrict__ bias, float* __restrict__ out) {
    int n = blockIdx.x;
    int f0 = (blockIdx.y * blockDim.x + threadIdx.x) * VPT;
    int start = offsets[n], end = offsets[n + 1];
    float acc[VPT];
#pragma unroll
    for (int v = 0; v < VPT; ++v) acc[v] = 0.f;
    const unsigned short* hb = (const unsigned short*)h;
    for (int j = start; j < end; ++j) {
        int sn = srcg[j];
        float a = ag[j];
        const unsigned short* hp = hb + (size_t)sn * F + f0;
        if constexpr (VPT == 2) {
            ushort2 u = *reinterpret_cast<const ushort2*>(hp);
            acc[0] += a * bfu2f(u.x);
            acc[1] += a * bfu2f(u.y);
        } else {
            acc[0] += a * bfu2f(*hp);
        }
    }
    float* orow = out + (size_t)n * F + f0;
#pragma unroll
    for (int v = 0; v < VPT; ++v) orow[v] = fmaxf(acc[v] + bias[f0 + v], 0.f);
}

// ---------------- global max pool (values >= 0 after relu) ----------------
__global__ void pool_kernel(const float* __restrict__ h, int N, float* __restrict__ pooled) {
    int b = blockIdx.x, tid = threadIdx.x;
    int chunk = (N + gridDim.x - 1) / gridDim.x;
    int r0 = b * chunk, r1 = r0 + chunk; if (r1 > N) r1 = N;
    float mx[4] = {0.f, 0.f, 0.f, 0.f};
    for (int r = r0; r < r1; ++r) {
        const float* row = h + (size_t)r * 1024;
#pragma unroll
        for (int q = 0; q < 4; ++q) mx[q] = fmaxf(mx[q], row[q * 256 + tid]);
    }
#pragma unroll
    for (int q = 0; q < 4; ++q)
        atomicMax((int*)&pooled[q * 256 + tid], __float_as_int(mx[q]));
}

// ---------------- dense head ----------------
__global__ void head1_kernel(const float* __restrict__ pooled, const float* __restrict__ lw1,
                             const float* __restrict__ lb1, float* __restrict__ z1) {
    int j = blockIdx.x * 256 + threadIdx.x;
    float acc = lb1[j];
    for (int k = 0; k < 1024; ++k) acc += pooled[k] * lw1[k * 512 + j];
    z1[j] = fmaxf(acc, 0.f);
}

__global__ void head2_kernel(const float* __restrict__ z1, const float* __restrict__ lw2,
                             const float* __restrict__ lb2, float* __restrict__ out) {
    __shared__ float z2[10];
    int tid = threadIdx.x;
    if (tid < 10) {
        float acc = lb2[tid];
        for (int k = 0; k < 512; ++k) acc += z1[k] * lw2[k * 10 + tid];
        z2[tid] = acc;
    }
    __syncthreads();
    if (tid == 0) {
        float m = z2[0];
        for (int j = 1; j < 10; ++j) m = fmaxf(m, z2[j]);
        float ssum = 0.f;
        for (int j = 0; j < 10; ++j) ssum += expf(z2[j] - m);
        float lse = m + logf(ssum);
        for (int j = 0; j < 10; ++j) out[j] = z2[j] - lse;
    }
}

extern "C" void kernel_launch(void* const* d_in, const int* in_sizes, int n_in,
                              void* d_out, int out_size, void* d_ws, size_t ws_size,
                              hipStream_t stream) {
    const float* x   = (const float*)d_in[0];
    const int* ei    = (const int*)d_in[1];
    const float* W1  = (const float*)d_in[3];
    const float* as1 = (const float*)d_in[4];
    const float* ad1 = (const float*)d_in[5];
    const float* b1  = (const float*)d_in[6];
    const float* W2  = (const float*)d_in[7];
    const float* as2 = (const float*)d_in[8];
    const float* ad2 = (const float*)d_in[9];
    const float* b2  = (const float*)d_in[10];
    const float* W3  = (const float*)d_in[11];
    const float* as3 = (const float*)d_in[12];
    const float* ad3 = (const float*)d_in[13];
    const float* b3  = (const float*)d_in[14];
    const float* lw1 = (const float*)d_in[15];
    const float* lb1 = (const float*)d_in[16];
    const float* lw2 = (const float*)d_in[17];
    const float* lb2 = (const float*)d_in[18];
    float* out = (float*)d_out;

    const int N = in_sizes[0] / 128;
    const int E = in_sizes[1] / 2;
    const int total = E + N;
    const int* esrc = ei;
    const int* edst = ei + E;

    float* ws = (float*)d_ws;
    float* abuf = ws;                                   // N*1024 f32
    __hip_bfloat16* hb16 = (__hip_bfloat16*)(abuf + (size_t)N * 1024); // N*1024 bf16
    float* after_h = (float*)((unsigned short*)hb16 + (size_t)N * 1024);
    float* sbuf   = after_h;               // N
    float* dbuf   = sbuf + N;              // N
    float* eg     = dbuf + N;              // total
    float* ag     = eg + total;            // total
    float* pooled = ag + total;            // 1024
    float* z1     = pooled + 1024;         // 512
    int* deg     = (int*)(z1 + 512);       // N
    int* cursor  = deg + N;                // N
    int* offsets = cursor + N;             // N+1
    int* eids    = offsets + N + 1;        // total
    int* srcg    = eids + total;           // total
    int* dstg    = srcg + total;           // total

    const int TPB = 256;
    int gN = (N + TPB - 1) / TPB;
    int gE = (total + TPB - 1) / TPB;
    int gW = (N + 3) / 4; // wave-per-node kernels

    // CSR build (depends only on edge_index)
    init_kernel<<<gN, TPB, 0, stream>>>(deg, cursor, pooled, N, 1024);
    count_kernel<<<gE, TPB, 0, stream>>>(edst, E, N, deg);
    scan_kernel<<<1, TPB, 0, stream>>>(deg, N, offsets);
    scatter_kernel<<<gE, TPB, 0, stream>>>(edst, E, N, offsets, cursor, eids);
    csr_meta_kernel<<<gE, TPB, 0, stream>>>(eids, esrc, edst, E, total, srcg, dstg);

    int gRows = (N + 63) / 64;

    // ---- layer 1: 128 -> 64 ----
    {
        dim3 grid(gRows, 1);
        gemm_kernel<<<grid, TPB, 0, stream>>>(x, W1, hb16, N, 128, 64);
        sd_kernel<<<gW, TPB, 0, stream>>>(hb16, as1, ad1, N, 64, sbuf, dbuf);
        edge_kernel<<<gE, TPB, 0, stream>>>(sbuf, dbuf, srcg, dstg, total, eg);
        mden_alpha_kernel<<<gW, TPB, 0, stream>>>(eg, offsets, N, ag);
        spmm_kernel<1><<<dim3(N, 1), 64, 0, stream>>>(hb16, ag, srcg, offsets, 64, b1, abuf);
    }
    // ---- layer 2: 64 -> 256 ----
    {
        dim3 grid(gRows, 4);
        gemm_kernel<<<grid, TPB, 0, stream>>>(abuf, W2, hb16, N, 64, 256);
        sd_kernel<<<gW, TPB, 0, stream>>>(hb16, as2, ad2, N, 256, sbuf, dbuf);
        edge_kernel<<<gE, TPB, 0, stream>>>(sbuf, dbuf, srcg, dstg, total, eg);
        mden_alpha_kernel<<<gW, TPB, 0, stream>>>(eg, offsets, N, ag);
        spmm_kernel<2><<<dim3(N, 1), 128, 0, stream>>>(hb16, ag, srcg, offsets, 256, b2, abuf);
    }
    // ---- layer 3: 256 -> 1024 ----
    {
        dim3 grid(gRows, 16);
        gemm_kernel<<<grid, TPB, 0, stream>>>(abuf, W3, hb16, N, 256, 1024);
        sd_kernel<<<gW, TPB, 0, stream>>>(hb16, as3, ad3, N, 1024, sbuf, dbuf);
        edge_kernel<<<gE, TPB, 0, stream>>>(sbuf, dbuf, srcg, dstg, total, eg);
        mden_alpha_kernel<<<gW, TPB, 0, stream>>>(eg, offsets, N, ag);
        spmm_kernel<2><<<dim3(N, 2), 256, 0, stream>>>(hb16, ag, srcg, offsets, 1024, b3, abuf);
    }
    // ---- pool + head ----
    pool_kernel<<<64, TPB, 0, stream>>>(abuf, N, pooled);
    head1_kernel<<<2, TPB, 0, stream>>>(pooled, lw1, lb1, z1);
    head2_kernel<<<1, 64, 0, stream>>>(z1, lw2, lb2, out);
}

// Round 3
// 293.545 us; speedup vs baseline: 2.1971x; 1.3640x over previous
//
#include <hip/hip_runtime.h>
#include <hip/hip_bf16.h>
#include <math.h>

#define NEG_SLOPE 0.2f
typedef unsigned short u16;
typedef short bf16x8 __attribute__((ext_vector_type(8)));
typedef float f32x4 __attribute__((ext_vector_type(4)));

__device__ __forceinline__ float bfu2f(u16 u) { return __uint_as_float(((unsigned)u) << 16); }
__device__ __forceinline__ u16 f2bu(float v) { return __bfloat16_as_ushort(__float2bfloat16(v)); }

// ---------------- init ----------------
__global__ void init_kernel(int* deg, int* cursor, float* pooled, int N, int P) {
    int i = blockIdx.x * blockDim.x + threadIdx.x;
    if (i < N) { deg[i] = 0; cursor[i] = 0; }
    if (i < P) pooled[i] = 0.f;
}

// ---------------- CSR build ----------------
__global__ void count_kernel(const int* __restrict__ edst, int E, int N, int* deg) {
    int i = blockIdx.x * blockDim.x + threadIdx.x;
    int total = E + N;
    if (i >= total) return;
    int dn = (i < E) ? edst[i] : (i - E);
    atomicAdd(&deg[dn], 1);
}

__global__ void scan_kernel(const int* __restrict__ deg, int N, int* __restrict__ offsets) {
    __shared__ int part[257];
    int tid = threadIdx.x;
    int chunk = (N + 255) / 256;
    int begin = tid * chunk;
    int fin = begin + chunk; if (fin > N) fin = N; if (begin > N) begin = N;
    int sum = 0;
    for (int i = begin; i < fin; ++i) sum += deg[i];
    part[tid] = sum;
    __syncthreads();
    if (tid == 0) {
        int acc = 0;
        for (int t = 0; t < 256; ++t) { int v = part[t]; part[t] = acc; acc += v; }
        part[256] = acc;
    }
    __syncthreads();
    int acc = part[tid];
    for (int i = begin; i < fin; ++i) { offsets[i] = acc; acc += deg[i]; }
    if (tid == 255) offsets[N] = part[256];
}

__global__ void scatter_kernel(const int* __restrict__ edst, int E, int N,
                               const int* __restrict__ offsets, int* cursor, int* eids) {
    int i = blockIdx.x * blockDim.x + threadIdx.x;
    int total = E + N;
    if (i >= total) return;
    int dn = (i < E) ? edst[i] : (i - E);
    int pos = atomicAdd(&cursor[dn], 1);
    eids[offsets[dn] + pos] = i;
}

__global__ void csr_meta_kernel(const int* __restrict__ eids, const int* __restrict__ esrc,
                                int E, int total, int* __restrict__ srcg) {
    int j = blockIdx.x * blockDim.x + threadIdx.x;
    if (j >= total) return;
    int eid = eids[j];
    srcg[j] = (eid < E) ? esrc[eid] : (eid - E);
}

// ---------------- fused conversions: x->bf16, W1/W2/W3 -> bf16 transposed ----------------
__global__ void cvt_kernel(const float* __restrict__ x, u16* __restrict__ xb, int nx,
                           const float* __restrict__ W1, u16* __restrict__ Wt1, int K1, int F1,
                           const float* __restrict__ W2, u16* __restrict__ Wt2, int K2, int F2,
                           const float* __restrict__ W3, u16* __restrict__ Wt3, int K3, int F3,
                           int bs1, int bs2, int bs3) {
    int bid = blockIdx.x, tid = threadIdx.x;
    if (bid < bs1) {
        int i = bid * 256 + tid;
        if (i < nx) xb[i] = f2bu(x[i]);
    } else if (bid < bs2) {
        int i = (bid - bs1) * 256 + tid;
        if (i < K1 * F1) { int k = i % K1, f = i / K1; Wt1[i] = f2bu(W1[(size_t)k * F1 + f]); }
    } else if (bid < bs3) {
        int i = (bid - bs2) * 256 + tid;
        if (i < K2 * F2) { int k = i % K2, f = i / K2; Wt2[i] = f2bu(W2[(size_t)k * F2 + f]); }
    } else {
        int i = (bid - bs3) * 256 + tid;
        if (i < K3 * F3) { int k = i % K3, f = i / K3; Wt3[i] = f2bu(W3[(size_t)k * F3 + f]); }
    }
}

// ---------------- ws[k] = sum_f W[k][f]*a_s[f]; wd likewise (layers 2,3) ----------------
__global__ void ws_kernel(const float* __restrict__ W2, const float* __restrict__ as2,
                          const float* __restrict__ ad2, int K2, int F2,
                          const float* __restrict__ W3, const float* __restrict__ as3,
                          const float* __restrict__ ad3, int K3, int F3,
                          float* __restrict__ ws2, float* __restrict__ wd2,
                          float* __restrict__ ws3, float* __restrict__ wd3) {
    int w = (blockIdx.x * blockDim.x + threadIdx.x) >> 6;
    int lane = threadIdx.x & 63;
    const float *W, *va, *vd; float *os, *od; int F, row;
    if (w < K2) { W = W2; va = as2; vd = ad2; F = F2; row = w; os = ws2; od = wd2; }
    else if (w < K2 + K3) { W = W3; va = as3; vd = ad3; F = F3; row = w - K2; os = ws3; od = wd3; }
    else return;
    const float* wr = W + (size_t)row * F;
    float ss = 0.f, dd = 0.f;
    for (int f = lane; f < F; f += 64) { float wv = wr[f]; ss += wv * va[f]; dd += wv * vd[f]; }
    for (int off = 32; off; off >>= 1) { ss += __shfl_xor(ss, off); dd += __shfl_xor(dd, off); }
    if (lane == 0) { os[row] = ss; od[row] = dd; }
}

// ---------------- MFMA GEMM: C[M][F] = A[M][K] @ Wt[F][K]^T, bf16 in/out ----------------
template <bool BIASRELU>
__global__ __launch_bounds__(256) void mfma_gemm(const u16* __restrict__ A,
                                                 const u16* __restrict__ Wt,
                                                 u16* __restrict__ C,
                                                 const float* __restrict__ bias,
                                                 int M, int K, int F) {
    int tid = threadIdx.x;
    int w = tid >> 6, l = tid & 63;
    int l15 = l & 15, q = l >> 4;
    int bm = blockIdx.x * 64;
    int bn = blockIdx.y * 64;
    int row = bm + w * 16 + l15;
    int arow = (row < M) ? row : (M - 1);
    f32x4 acc[4];
#pragma unroll
    for (int nt = 0; nt < 4; ++nt) acc[nt] = (f32x4){0.f, 0.f, 0.f, 0.f};
    for (int k0 = 0; k0 < K; k0 += 32) {
        bf16x8 a8 = *(const bf16x8*)(A + (size_t)arow * K + k0 + 8 * q);
#pragma unroll
        for (int nt = 0; nt < 4; ++nt) {
            bf16x8 b8 = *(const bf16x8*)(Wt + (size_t)(bn + nt * 16 + l15) * K + k0 + 8 * q);
            // D(lane,reg): node-row = l&15 (arg2), feature-col = 4*(l>>4)+reg (arg1)
            acc[nt] = __builtin_amdgcn_mfma_f32_16x16x32_bf16(b8, a8, acc[nt], 0, 0, 0);
        }
    }
    if (row >= M) return;
#pragma unroll
    for (int nt = 0; nt < 4; ++nt) {
        int col = bn + nt * 16 + 4 * q;
        ushort4 st;
#pragma unroll
        for (int r = 0; r < 4; ++r) {
            float v = acc[nt][r];
            if (BIASRELU) { v += bias[col + r]; v = fmaxf(v, 0.f); }
            ((u16*)&st)[r] = f2bu(v);
        }
        *(ushort4*)(C + (size_t)row * F + col) = st;
    }
}

// ---------------- s[n]=h[n]. va, d[n]=h[n] . vb (bf16 rows, f32 vecs) ----------------
__global__ void sd_kernel(const u16* __restrict__ h, const float* __restrict__ a_s,
                          const float* __restrict__ a_d, int N, int F,
                          float* __restrict__ s, float* __restrict__ d) {
    int wave = (blockIdx.x * blockDim.x + threadIdx.x) >> 6;
    int lane = threadIdx.x & 63;
    if (wave >= N) return;
    const u16* hrow = h + (size_t)wave * F;
    float ss = 0.f, dd = 0.f;
    for (int f = lane * 4; f < F; f += 256) {
        ushort4 u = *reinterpret_cast<const ushort4*>(hrow + f);
        float4 av = *reinterpret_cast<const float4*>(a_s + f);
        float4 dv = *reinterpret_cast<const float4*>(a_d + f);
        float h0 = bfu2f(u.x), h1 = bfu2f(u.y), h2 = bfu2f(u.z), h3 = bfu2f(u.w);
        ss += h0 * av.x + h1 * av.y + h2 * av.z + h3 * av.w;
        dd += h0 * dv.x + h1 * dv.y + h2 * dv.z + h3 * dv.w;
    }
    for (int off = 32; off; off >>= 1) { ss += __shfl_xor(ss, off); dd += __shfl_xor(dd, off); }
    if (lane == 0) { s[wave] = ss; d[wave] = dd; }
}

// ---------------- fused edge-logit + scatter-softmax: alpha in CSR order ----------------
__global__ void alpha_kernel(const float* __restrict__ s, const float* __restrict__ d,
                             const int* __restrict__ srcg, const int* __restrict__ offsets,
                             int N, float* __restrict__ ag) {
    int n = (blockIdx.x * blockDim.x + threadIdx.x) >> 6;
    int lane = threadIdx.x & 63;
    if (n >= N) return;
    int start = offsets[n], end = offsets[n + 1];
    float dval = d[n];
    int j0 = start + lane;
    float e0 = -INFINITY;
    if (j0 < end) { float v = s[srcg[j0]] + dval; e0 = (v >= 0.f) ? v : NEG_SLOPE * v; }
    float lmax = e0;
    for (int j = j0 + 64; j < end; j += 64) {
        float v = s[srcg[j]] + dval; v = (v >= 0.f) ? v : NEG_SLOPE * v;
        lmax = fmaxf(lmax, v);
    }
    for (int off = 32; off; off >>= 1) lmax = fmaxf(lmax, __shfl_xor(lmax, off));
    float ls = (j0 < end) ? expf(e0 - lmax) : 0.f;
    for (int j = j0 + 64; j < end; j += 64) {
        float v = s[srcg[j]] + dval; v = (v >= 0.f) ? v : NEG_SLOPE * v;
        ls += expf(v - lmax);
    }
    for (int off = 32; off; off >>= 1) ls += __shfl_xor(ls, off);
    float inv = 1.f / ls;
    if (j0 < end) ag[j0] = expf(e0 - lmax) * inv;
    for (int j = j0 + 64; j < end; j += 64) {
        float v = s[srcg[j]] + dval; v = (v >= 0.f) ? v : NEG_SLOPE * v;
        ag[j] = expf(v - lmax) * inv;
    }
}

// ---------------- SpMM gather: out[n] = sum_j alpha_j * h[src_j] (+bias,relu), bf16 out ----------------
template <int VPT, bool BIASRELU>
__global__ void spmm_kernel(const u16* __restrict__ h, const float* __restrict__ ag,
                            const int* __restrict__ srcg, const int* __restrict__ offsets,
                            int F, const float* __restrict__ bias, u16* __restrict__ out) {
    int n = blockIdx.x;
    int f0 = threadIdx.x * VPT;
    int start = offsets[n], end = offsets[n + 1];
    float acc[VPT];
#pragma unroll
    for (int v = 0; v < VPT; ++v) acc[v] = 0.f;
    for (int j = start; j < end; ++j) {
        int sn = srcg[j];
        float a = ag[j];
        const u16* hp = h + (size_t)sn * F + f0;
        if constexpr (VPT == 2) {
            ushort2 u = *reinterpret_cast<const ushort2*>(hp);
            acc[0] += a * bfu2f(u.x);
            acc[1] += a * bfu2f(u.y);
        } else {
            acc[0] += a * bfu2f(*hp);
        }
    }
    u16* orow = out + (size_t)n * F + f0;
#pragma unroll
    for (int v = 0; v < VPT; ++v) {
        float x = acc[v];
        if (BIASRELU) { x += bias[f0 + v]; x = fmaxf(x, 0.f); }
        orow[v] = f2bu(x);
    }
}

// ---------------- global max pool over bf16 h3 ----------------
__global__ void pool_kernel(const u16* __restrict__ h, int N, float* __restrict__ pooled) {
    int b = blockIdx.x, tid = threadIdx.x;
    int chunk = (N + gridDim.x - 1) / gridDim.x;
    int r0 = b * chunk, r1 = r0 + chunk; if (r1 > N) r1 = N;
    float mx[4] = {0.f, 0.f, 0.f, 0.f};
    for (int r = r0; r < r1; ++r) {
        const u16* row = h + (size_t)r * 1024;
#pragma unroll
        for (int q = 0; q < 4; ++q) mx[q] = fmaxf(mx[q], bfu2f(row[q * 256 + tid]));
    }
#pragma unroll
    for (int q = 0; q < 4; ++q)
        atomicMax((int*)&pooled[q * 256 + tid], __float_as_int(mx[q]));
}

// ---------------- dense head ----------------
__global__ void head1_kernel(const float* __restrict__ pooled, const float* __restrict__ lw1,
                             const float* __restrict__ lb1, float* __restrict__ z1) {
    int j = blockIdx.x * 128 + threadIdx.x; // 512 outputs, 4 blocks x 128
    float acc = lb1[j];
    for (int k = 0; k < 1024; ++k) acc += pooled[k] * lw1[k * 512 + j];
    z1[j] = fmaxf(acc, 0.f);
}

__global__ void head2_kernel(const float* __restrict__ z1, const float* __restrict__ lw2,
                             const float* __restrict__ lb2, float* __restrict__ out) {
    __shared__ float z2[10];
    int tid = threadIdx.x;
    if (tid < 10) {
        float acc = lb2[tid];
        for (int k = 0; k < 512; ++k) acc += z1[k] * lw2[k * 10 + tid];
        z2[tid] = acc;
    }
    __syncthreads();
    if (tid == 0) {
        float m = z2[0];
        for (int j = 1; j < 10; ++j) m = fmaxf(m, z2[j]);
        float ssum = 0.f;
        for (int j = 0; j < 10; ++j) ssum += expf(z2[j] - m);
        float lse = m + logf(ssum);
        for (int j = 0; j < 10; ++j) out[j] = z2[j] - lse;
    }
}

extern "C" void kernel_launch(void* const* d_in, const int* in_sizes, int n_in,
                              void* d_out, int out_size, void* d_ws, size_t ws_size,
                              hipStream_t stream) {
    const float* x   = (const float*)d_in[0];
    const int* ei    = (const int*)d_in[1];
    const float* W1  = (const float*)d_in[3];
    const float* as1 = (const float*)d_in[4];
    const float* ad1 = (const float*)d_in[5];
    const float* b1  = (const float*)d_in[6];
    const float* W2  = (const float*)d_in[7];
    const float* as2 = (const float*)d_in[8];
    const float* ad2 = (const float*)d_in[9];
    const float* b2  = (const float*)d_in[10];
    const float* W3  = (const float*)d_in[11];
    const float* as3 = (const float*)d_in[12];
    const float* ad3 = (const float*)d_in[13];
    const float* b3  = (const float*)d_in[14];
    const float* lw1 = (const float*)d_in[15];
    const float* lb1 = (const float*)d_in[16];
    const float* lw2 = (const float*)d_in[17];
    const float* lb2 = (const float*)d_in[18];
    float* out = (float*)d_out;

    const int N = in_sizes[0] / 128;
    const int E = in_sizes[1] / 2;
    const int total = E + N;
    const int* esrc = ei;
    const int* edst = ei + E;

    // bump allocator on d_ws, 256B aligned
    char* base = (char*)d_ws;
    size_t off = 0;
    auto alloc = [&](size_t bytes) { void* p = base + off; off = (off + bytes + 255) & ~(size_t)255; return p; };
    u16* xb   = (u16*)alloc((size_t)N * 128 * 2);
    u16* h1   = (u16*)alloc((size_t)N * 64 * 2);
    u16* a1   = (u16*)alloc((size_t)N * 64 * 2);
    u16* agg2 = (u16*)alloc((size_t)N * 64 * 2);
    u16* a2   = (u16*)alloc((size_t)N * 256 * 2);
    u16* agg3 = (u16*)alloc((size_t)N * 256 * 2);
    u16* h3   = (u16*)alloc((size_t)N * 1024 * 2);
    u16* Wt1  = (u16*)alloc(128 * 64 * 2);
    u16* Wt2  = (u16*)alloc(64 * 256 * 2);
    u16* Wt3  = (u16*)alloc(256 * 1024 * 2);
    float* ws2 = (float*)alloc(64 * 4);
    float* wd2 = (float*)alloc(64 * 4);
    float* ws3 = (float*)alloc(256 * 4);
    float* wd3 = (float*)alloc(256 * 4);
    float* sbuf = (float*)alloc((size_t)N * 4);
    float* dbuf = (float*)alloc((size_t)N * 4);
    float* ag   = (float*)alloc((size_t)total * 4);
    float* pooled = (float*)alloc(1024 * 4);
    float* z1     = (float*)alloc(512 * 4);
    int* deg     = (int*)alloc((size_t)N * 4);
    int* cursor  = (int*)alloc((size_t)N * 4);
    int* offsets = (int*)alloc((size_t)(N + 1) * 4);
    int* eids    = (int*)alloc((size_t)total * 4);
    int* srcg    = (int*)alloc((size_t)total * 4);

    const int TPB = 256;
    int gN = (N + TPB - 1) / TPB;
    int gE = (total + TPB - 1) / TPB;
    int gW = (N + 3) / 4;           // wave-per-node
    int gRows = (N + 63) / 64;      // GEMM row tiles

    // CSR build
    init_kernel<<<gN, TPB, 0, stream>>>(deg, cursor, pooled, N, 1024);
    count_kernel<<<gE, TPB, 0, stream>>>(edst, E, N, deg);
    scan_kernel<<<1, TPB, 0, stream>>>(deg, N, offsets);
    scatter_kernel<<<gE, TPB, 0, stream>>>(edst, E, N, offsets, cursor, eids);
    csr_meta_kernel<<<gE, TPB, 0, stream>>>(eids, esrc, E, total, srcg);

    // conversions
    int nx = N * 128;
    int bs1 = (nx + 255) / 256;
    int bs2 = bs1 + (128 * 64 + 255) / 256;
    int bs3 = bs2 + (64 * 256 + 255) / 256;
    int gC = bs3 + (256 * 1024 + 255) / 256;
    cvt_kernel<<<gC, TPB, 0, stream>>>(x, xb, nx, W1, Wt1, 128, 64,
                                       W2, Wt2, 64, 256, W3, Wt3, 256, 1024,
                                       bs1, bs2, bs3);
    ws_kernel<<<(64 + 256 + 3) / 4, TPB, 0, stream>>>(W2, as2, ad2, 64, 256,
                                                      W3, as3, ad3, 256, 1024,
                                                      ws2, wd2, ws3, wd3);

    // ---- layer 1: gemm first (gather in 64-dim h1) ----
    mfma_gemm<false><<<dim3(gRows, 1), TPB, 0, stream>>>(xb, Wt1, h1, nullptr, N, 128, 64);
    sd_kernel<<<gW, TPB, 0, stream>>>(h1, as1, ad1, N, 64, sbuf, dbuf);
    alpha_kernel<<<gW, TPB, 0, stream>>>(sbuf, dbuf, srcg, offsets, N, ag);
    spmm_kernel<1, true><<<N, 64, 0, stream>>>(h1, ag, srcg, offsets, 64, b1, a1);

    // ---- layer 2: aggregate-then-gemm ----
    sd_kernel<<<gW, TPB, 0, stream>>>(a1, ws2, wd2, N, 64, sbuf, dbuf);
    alpha_kernel<<<gW, TPB, 0, stream>>>(sbuf, dbuf, srcg, offsets, N, ag);
    spmm_kernel<1, false><<<N, 64, 0, stream>>>(a1, ag, srcg, offsets, 64, nullptr, agg2);
    mfma_gemm<true><<<dim3(gRows, 4), TPB, 0, stream>>>(agg2, Wt2, a2, b2, N, 64, 256);

    // ---- layer 3: aggregate-then-gemm ----
    sd_kernel<<<gW, TPB, 0, stream>>>(a2, ws3, wd3, N, 256, sbuf, dbuf);
    alpha_kernel<<<gW, TPB, 0, stream>>>(sbuf, dbuf, srcg, offsets, N, ag);
    spmm_kernel<2, false><<<N, 128, 0, stream>>>(a2, ag, srcg, offsets, 256, nullptr, agg3);
    mfma_gemm<true><<<dim3(gRows, 16), TPB, 0, stream>>>(agg3, Wt3, h3, b3, N, 256, 1024);

    // ---- pool + head ----
    pool_kernel<<<256, TPB, 0, stream>>>(h3, N, pooled);
    head1_kernel<<<4, 128, 0, stream>>>(pooled, lw1, lb1, z1);
    head2_kernel<<<1, 64, 0, stream>>>(z1, lw2, lb2, out);
}

// Round 4
// 228.953 us; speedup vs baseline: 2.8170x; 1.2821x over previous
//
#include <hip/hip_runtime.h>
#include <hip/hip_bf16.h>
#include <math.h>

#define NEG_SLOPE 0.2f
typedef unsigned short u16;
typedef short bf16x8 __attribute__((ext_vector_type(8)));
typedef float f32x4 __attribute__((ext_vector_type(4)));

__device__ __forceinline__ float bfu2f(u16 u) { return __uint_as_float(((unsigned)u) << 16); }
__device__ __forceinline__ u16 f2bu(float v) { return __bfloat16_as_ushort(__float2bfloat16(v)); }

// ---------------- init ----------------
__global__ void init_kernel(int* deg, int* cursor, float* pooled, int N, int P) {
    int i = blockIdx.x * blockDim.x + threadIdx.x;
    if (i < N) { deg[i] = 0; cursor[i] = 0; }
    if (i < P) pooled[i] = 0.f;
}

// ---------------- CSR build ----------------
__global__ void count_kernel(const int* __restrict__ edst, int E, int N, int* deg) {
    int i = blockIdx.x * blockDim.x + threadIdx.x;
    int total = E + N;
    if (i >= total) return;
    int dn = (i < E) ? edst[i] : (i - E);
    atomicAdd(&deg[dn], 1);
}

__global__ void scan_kernel(const int* __restrict__ deg, int N, int* __restrict__ offsets) {
    __shared__ int part[257];
    int tid = threadIdx.x;
    int chunk = (N + 255) / 256;
    int begin = tid * chunk;
    int fin = begin + chunk; if (fin > N) fin = N; if (begin > N) begin = N;
    int sum = 0;
    for (int i = begin; i < fin; ++i) sum += deg[i];
    part[tid] = sum;
    __syncthreads();
    if (tid == 0) {
        int acc = 0;
        for (int t = 0; t < 256; ++t) { int v = part[t]; part[t] = acc; acc += v; }
        part[256] = acc;
    }
    __syncthreads();
    int acc = part[tid];
    for (int i = begin; i < fin; ++i) { offsets[i] = acc; acc += deg[i]; }
    if (tid == 255) offsets[N] = part[256];
}

__global__ void scatter_kernel(const int* __restrict__ edst, int E, int N,
                               const int* __restrict__ offsets, int* cursor, int* eids) {
    int i = blockIdx.x * blockDim.x + threadIdx.x;
    int total = E + N;
    if (i >= total) return;
    int dn = (i < E) ? edst[i] : (i - E);
    int pos = atomicAdd(&cursor[dn], 1);
    eids[offsets[dn] + pos] = i;
}

__global__ void csr_meta_kernel(const int* __restrict__ eids, const int* __restrict__ esrc,
                                int E, int total, int* __restrict__ srcg) {
    int j = blockIdx.x * blockDim.x + threadIdx.x;
    if (j >= total) return;
    int eid = eids[j];
    srcg[j] = (eid < E) ? esrc[eid] : (eid - E);
}

// ---------------- fused conversions: x->bf16, W1/W2/W3 -> bf16 transposed ----------------
__global__ void cvt_kernel(const float* __restrict__ x, u16* __restrict__ xb, int nx,
                           const float* __restrict__ W1, u16* __restrict__ Wt1, int K1, int F1,
                           const float* __restrict__ W2, u16* __restrict__ Wt2, int K2, int F2,
                           const float* __restrict__ W3, u16* __restrict__ Wt3, int K3, int F3,
                           int bs1, int bs2, int bs3) {
    int bid = blockIdx.x, tid = threadIdx.x;
    if (bid < bs1) {
        int i = bid * 256 + tid;
        if (i < nx) xb[i] = f2bu(x[i]);
    } else if (bid < bs2) {
        int i = (bid - bs1) * 256 + tid;
        if (i < K1 * F1) { int k = i % K1, f = i / K1; Wt1[i] = f2bu(W1[(size_t)k * F1 + f]); }
    } else if (bid < bs3) {
        int i = (bid - bs2) * 256 + tid;
        if (i < K2 * F2) { int k = i % K2, f = i / K2; Wt2[i] = f2bu(W2[(size_t)k * F2 + f]); }
    } else {
        int i = (bid - bs3) * 256 + tid;
        if (i < K3 * F3) { int k = i % K3, f = i / K3; Wt3[i] = f2bu(W3[(size_t)k * F3 + f]); }
    }
}

// ---------------- ws[k] = sum_f W[k][f]*a_s[f]; wd likewise (layers 2,3) ----------------
__global__ void ws_kernel(const float* __restrict__ W2, const float* __restrict__ as2,
                          const float* __restrict__ ad2, int K2, int F2,
                          const float* __restrict__ W3, const float* __restrict__ as3,
                          const float* __restrict__ ad3, int K3, int F3,
                          float* __restrict__ ws2, float* __restrict__ wd2,
                          float* __restrict__ ws3, float* __restrict__ wd3) {
    int w = (blockIdx.x * blockDim.x + threadIdx.x) >> 6;
    int lane = threadIdx.x & 63;
    const float *W, *va, *vd; float *os, *od; int F, row;
    if (w < K2) { W = W2; va = as2; vd = ad2; F = F2; row = w; os = ws2; od = wd2; }
    else if (w < K2 + K3) { W = W3; va = as3; vd = ad3; F = F3; row = w - K2; os = ws3; od = wd3; }
    else return;
    const float* wr = W + (size_t)row * F;
    float ss = 0.f, dd = 0.f;
    for (int f = lane; f < F; f += 64) { float wv = wr[f]; ss += wv * va[f]; dd += wv * vd[f]; }
    for (int off = 32; off; off >>= 1) { ss += __shfl_xor(ss, off); dd += __shfl_xor(dd, off); }
    if (lane == 0) { os[row] = ss; od[row] = dd; }
}

// ---------------- MFMA GEMM: C[M][F] = A[M][K] @ Wt[F][K]^T, bf16 in/out ----------------
// Compile-time K (full unroll) + MR row-frags per wave + register prefetch.
template <int K, int MR, bool BIASRELU>
__global__ __launch_bounds__(256) void mfma_gemm(const u16* __restrict__ A,
                                                 const u16* __restrict__ Wt,
                                                 u16* __restrict__ C,
                                                 const float* __restrict__ bias,
                                                 int M, int F) {
    constexpr int NK = K / 32;
    int tid = threadIdx.x;
    int w = tid >> 6, l = tid & 63;
    int l15 = l & 15, q = l >> 4;
    int bm = blockIdx.x * (64 * MR);
    int bn = blockIdx.y * 64;
    int r0 = bm + w * (16 * MR);

    const u16* aptr[MR];
    int row[MR];
#pragma unroll
    for (int mr = 0; mr < MR; ++mr) {
        int r = r0 + mr * 16 + l15;
        row[mr] = r;
        int ar = (r < M) ? r : (M - 1);
        aptr[mr] = A + (size_t)ar * K + 8 * q;
    }
    const u16* bptr[4];
#pragma unroll
    for (int nt = 0; nt < 4; ++nt)
        bptr[nt] = Wt + (size_t)(bn + nt * 16 + l15) * K + 8 * q;

    f32x4 acc[MR][4];
#pragma unroll
    for (int mr = 0; mr < MR; ++mr)
#pragma unroll
        for (int nt = 0; nt < 4; ++nt) acc[mr][nt] = (f32x4){0.f, 0.f, 0.f, 0.f};

    bf16x8 a_cur[MR], b_cur[4], a_nxt[MR], b_nxt[4];
#pragma unroll
    for (int mr = 0; mr < MR; ++mr) a_cur[mr] = *(const bf16x8*)(aptr[mr]);
#pragma unroll
    for (int nt = 0; nt < 4; ++nt) b_cur[nt] = *(const bf16x8*)(bptr[nt]);

#pragma unroll
    for (int kk = 0; kk < NK; ++kk) {
        if (kk + 1 < NK) {
            int koff = (kk + 1) * 32;
#pragma unroll
            for (int mr = 0; mr < MR; ++mr) a_nxt[mr] = *(const bf16x8*)(aptr[mr] + koff);
#pragma unroll
            for (int nt = 0; nt < 4; ++nt) b_nxt[nt] = *(const bf16x8*)(bptr[nt] + koff);
        }
#pragma unroll
        for (int mr = 0; mr < MR; ++mr)
#pragma unroll
            for (int nt = 0; nt < 4; ++nt)
                acc[mr][nt] = __builtin_amdgcn_mfma_f32_16x16x32_bf16(b_cur[nt], a_cur[mr], acc[mr][nt], 0, 0, 0);
        if (kk + 1 < NK) {
#pragma unroll
            for (int mr = 0; mr < MR; ++mr) a_cur[mr] = a_nxt[mr];
#pragma unroll
            for (int nt = 0; nt < 4; ++nt) b_cur[nt] = b_nxt[nt];
        }
    }

#pragma unroll
    for (int mr = 0; mr < MR; ++mr) {
        if (row[mr] >= M) continue;
#pragma unroll
        for (int nt = 0; nt < 4; ++nt) {
            int col = bn + nt * 16 + 4 * q;
            ushort4 st;
#pragma unroll
            for (int r = 0; r < 4; ++r) {
                float v = acc[mr][nt][r];
                if (BIASRELU) { v += bias[col + r]; v = fmaxf(v, 0.f); }
                ((u16*)&st)[r] = f2bu(v);
            }
            *(ushort4*)(C + (size_t)row[mr] * F + col) = st;
        }
    }
}

// ---------------- s[n]=h[n]. va, d[n]=h[n] . vb (bf16 rows, f32 vecs) ----------------
__global__ void sd_kernel(const u16* __restrict__ h, const float* __restrict__ a_s,
                          const float* __restrict__ a_d, int N, int F,
                          float* __restrict__ s, float* __restrict__ d) {
    int wave = (blockIdx.x * blockDim.x + threadIdx.x) >> 6;
    int lane = threadIdx.x & 63;
    if (wave >= N) return;
    const u16* hrow = h + (size_t)wave * F;
    float ss = 0.f, dd = 0.f;
    for (int f = lane * 4; f < F; f += 256) {
        ushort4 u = *reinterpret_cast<const ushort4*>(hrow + f);
        float4 av = *reinterpret_cast<const float4*>(a_s + f);
        float4 dv = *reinterpret_cast<const float4*>(a_d + f);
        float h0 = bfu2f(u.x), h1 = bfu2f(u.y), h2 = bfu2f(u.z), h3 = bfu2f(u.w);
        ss += h0 * av.x + h1 * av.y + h2 * av.z + h3 * av.w;
        dd += h0 * dv.x + h1 * dv.y + h2 * dv.z + h3 * dv.w;
    }
    for (int off = 32; off; off >>= 1) { ss += __shfl_xor(ss, off); dd += __shfl_xor(dd, off); }
    if (lane == 0) { s[wave] = ss; d[wave] = dd; }
}

// ---------------- fused edge-logit + scatter-softmax: alpha in CSR order ----------------
__global__ void alpha_kernel(const float* __restrict__ s, const float* __restrict__ d,
                             const int* __restrict__ srcg, const int* __restrict__ offsets,
                             int N, float* __restrict__ ag) {
    int n = (blockIdx.x * blockDim.x + threadIdx.x) >> 6;
    int lane = threadIdx.x & 63;
    if (n >= N) return;
    int start = offsets[n], end = offsets[n + 1];
    float dval = d[n];
    int j0 = start + lane;
    float e0 = -INFINITY;
    if (j0 < end) { float v = s[srcg[j0]] + dval; e0 = (v >= 0.f) ? v : NEG_SLOPE * v; }
    float lmax = e0;
    for (int j = j0 + 64; j < end; j += 64) {
        float v = s[srcg[j]] + dval; v = (v >= 0.f) ? v : NEG_SLOPE * v;
        lmax = fmaxf(lmax, v);
    }
    for (int off = 32; off; off >>= 1) lmax = fmaxf(lmax, __shfl_xor(lmax, off));
    float ls = (j0 < end) ? expf(e0 - lmax) : 0.f;
    for (int j = j0 + 64; j < end; j += 64) {
        float v = s[srcg[j]] + dval; v = (v >= 0.f) ? v : NEG_SLOPE * v;
        ls += expf(v - lmax);
    }
    for (int off = 32; off; off >>= 1) ls += __shfl_xor(ls, off);
    float inv = 1.f / ls;
    if (j0 < end) ag[j0] = expf(e0 - lmax) * inv;
    for (int j = j0 + 64; j < end; j += 64) {
        float v = s[srcg[j]] + dval; v = (v >= 0.f) ? v : NEG_SLOPE * v;
        ag[j] = expf(v - lmax) * inv;
    }
}

// ---------------- SpMM gather: out[n] = sum_j alpha_j * h[src_j] (+bias,relu), bf16 out ----------------
template <int VPT, bool BIASRELU>
__global__ void spmm_kernel(const u16* __restrict__ h, const float* __restrict__ ag,
                            const int* __restrict__ srcg, const int* __restrict__ offsets,
                            int F, const float* __restrict__ bias, u16* __restrict__ out) {
    int n = blockIdx.x;
    int f0 = threadIdx.x * VPT;
    int start = offsets[n], end = offsets[n + 1];
    float acc[VPT];
#pragma unroll
    for (int v = 0; v < VPT; ++v) acc[v] = 0.f;
    for (int j = start; j < end; ++j) {
        int sn = srcg[j];
        float a = ag[j];
        const u16* hp = h + (size_t)sn * F + f0;
        if constexpr (VPT == 2) {
            ushort2 u = *reinterpret_cast<const ushort2*>(hp);
            acc[0] += a * bfu2f(u.x);
            acc[1] += a * bfu2f(u.y);
        } else {
            acc[0] += a * bfu2f(*hp);
        }
    }
    u16* orow = out + (size_t)n * F + f0;
#pragma unroll
    for (int v = 0; v < VPT; ++v) {
        float x = acc[v];
        if (BIASRELU) { x += bias[f0 + v]; x = fmaxf(x, 0.f); }
        orow[v] = f2bu(x);
    }
}

// ---------------- global max pool over bf16 h3 ----------------
__global__ void pool_kernel(const u16* __restrict__ h, int N, float* __restrict__ pooled) {
    int b = blockIdx.x, tid = threadIdx.x;
    int chunk = (N + gridDim.x - 1) / gridDim.x;
    int r0 = b * chunk, r1 = r0 + chunk; if (r1 > N) r1 = N;
    float mx[4] = {0.f, 0.f, 0.f, 0.f};
    for (int r = r0; r < r1; ++r) {
        const u16* row = h + (size_t)r * 1024;
#pragma unroll
        for (int q = 0; q < 4; ++q) mx[q] = fmaxf(mx[q], bfu2f(row[q * 256 + tid]));
    }
#pragma unroll
    for (int q = 0; q < 4; ++q)
        atomicMax((int*)&pooled[q * 256 + tid], __float_as_int(mx[q]));
}

// ---------------- dense head: z1 = relu(pooled @ lw1 + lb1), k-split 2 phase ----------------
__global__ void head1a_kernel(const float* __restrict__ pooled, const float* __restrict__ lw1,
                              float* __restrict__ part) {
    // grid (4, 16), block 128: j = bx*128+tx, k-chunk = by*64
    int j = blockIdx.x * 128 + threadIdx.x;
    int k0 = blockIdx.y * 64;
    float acc = 0.f;
#pragma unroll 8
    for (int k = k0; k < k0 + 64; ++k) acc += pooled[k] * lw1[(size_t)k * 512 + j];
    part[blockIdx.y * 512 + j] = acc;
}

__global__ void head1b_kernel(const float* __restrict__ part, const float* __restrict__ lb1,
                              float* __restrict__ z1) {
    int j = blockIdx.x * 128 + threadIdx.x;
    float acc = lb1[j];
#pragma unroll
    for (int t = 0; t < 16; ++t) acc += part[t * 512 + j];
    z1[j] = fmaxf(acc, 0.f);
}

__global__ void head2_kernel(const float* __restrict__ z1, const float* __restrict__ lw2,
                             const float* __restrict__ lb2, float* __restrict__ out) {
    __shared__ float z2[10];
    int tid = threadIdx.x;
    if (tid < 10) {
        float acc = lb2[tid];
        for (int k = 0; k < 512; ++k) acc += z1[k] * lw2[k * 10 + tid];
        z2[tid] = acc;
    }
    __syncthreads();
    if (tid == 0) {
        float m = z2[0];
        for (int j = 1; j < 10; ++j) m = fmaxf(m, z2[j]);
        float ssum = 0.f;
        for (int j = 0; j < 10; ++j) ssum += expf(z2[j] - m);
        float lse = m + logf(ssum);
        for (int j = 0; j < 10; ++j) out[j] = z2[j] - lse;
    }
}

extern "C" void kernel_launch(void* const* d_in, const int* in_sizes, int n_in,
                              void* d_out, int out_size, void* d_ws, size_t ws_size,
                              hipStream_t stream) {
    const float* x   = (const float*)d_in[0];
    const int* ei    = (const int*)d_in[1];
    const float* W1  = (const float*)d_in[3];
    const float* as1 = (const float*)d_in[4];
    const float* ad1 = (const float*)d_in[5];
    const float* b1  = (const float*)d_in[6];
    const float* W2  = (const float*)d_in[7];
    const float* as2 = (const float*)d_in[8];
    const float* ad2 = (const float*)d_in[9];
    const float* b2  = (const float*)d_in[10];
    const float* W3  = (const float*)d_in[11];
    const float* as3 = (const float*)d_in[12];
    const float* ad3 = (const float*)d_in[13];
    const float* b3  = (const float*)d_in[14];
    const float* lw1 = (const float*)d_in[15];
    const float* lb1 = (const float*)d_in[16];
    const float* lw2 = (const float*)d_in[17];
    const float* lb2 = (const float*)d_in[18];
    float* out = (float*)d_out;

    const int N = in_sizes[0] / 128;
    const int E = in_sizes[1] / 2;
    const int total = E + N;
    const int* esrc = ei;
    const int* edst = ei + E;

    // bump allocator on d_ws, 256B aligned
    char* base = (char*)d_ws;
    size_t off = 0;
    auto alloc = [&](size_t bytes) { void* p = base + off; off = (off + bytes + 255) & ~(size_t)255; return p; };
    u16* xb   = (u16*)alloc((size_t)N * 128 * 2);
    u16* h1   = (u16*)alloc((size_t)N * 64 * 2);
    u16* a1   = (u16*)alloc((size_t)N * 64 * 2);
    u16* agg2 = (u16*)alloc((size_t)N * 64 * 2);
    u16* a2   = (u16*)alloc((size_t)N * 256 * 2);
    u16* agg3 = (u16*)alloc((size_t)N * 256 * 2);
    u16* h3   = (u16*)alloc((size_t)N * 1024 * 2);
    u16* Wt1  = (u16*)alloc(128 * 64 * 2);
    u16* Wt2  = (u16*)alloc(64 * 256 * 2);
    u16* Wt3  = (u16*)alloc(256 * 1024 * 2);
    float* ws2 = (float*)alloc(64 * 4);
    float* wd2 = (float*)alloc(64 * 4);
    float* ws3 = (float*)alloc(256 * 4);
    float* wd3 = (float*)alloc(256 * 4);
    float* sbuf = (float*)alloc((size_t)N * 4);
    float* dbuf = (float*)alloc((size_t)N * 4);
    float* ag   = (float*)alloc((size_t)total * 4);
    float* pooled = (float*)alloc(1024 * 4);
    float* z1     = (float*)alloc(512 * 4);
    float* hpart  = (float*)alloc(16 * 512 * 4);
    int* deg     = (int*)alloc((size_t)N * 4);
    int* cursor  = (int*)alloc((size_t)N * 4);
    int* offsets = (int*)alloc((size_t)(N + 1) * 4);
    int* eids    = (int*)alloc((size_t)total * 4);
    int* srcg    = (int*)alloc((size_t)total * 4);

    const int TPB = 256;
    int gN = (N + TPB - 1) / TPB;
    int gE = (total + TPB - 1) / TPB;
    int gW = (N + 3) / 4;             // wave-per-node
    int gR64 = (N + 63) / 64;         // 64-row tiles
    int gR128 = (N + 127) / 128;      // 128-row tiles

    // CSR build
    init_kernel<<<gN, TPB, 0, stream>>>(deg, cursor, pooled, N, 1024);
    count_kernel<<<gE, TPB, 0, stream>>>(edst, E, N, deg);
    scan_kernel<<<1, TPB, 0, stream>>>(deg, N, offsets);
    scatter_kernel<<<gE, TPB, 0, stream>>>(edst, E, N, offsets, cursor, eids);
    csr_meta_kernel<<<gE, TPB, 0, stream>>>(eids, esrc, E, total, srcg);

    // conversions
    int nx = N * 128;
    int bs1 = (nx + 255) / 256;
    int bs2 = bs1 + (128 * 64 + 255) / 256;
    int bs3 = bs2 + (64 * 256 + 255) / 256;
    int gC = bs3 + (256 * 1024 + 255) / 256;
    cvt_kernel<<<gC, TPB, 0, stream>>>(x, xb, nx, W1, Wt1, 128, 64,
                                       W2, Wt2, 64, 256, W3, Wt3, 256, 1024,
                                       bs1, bs2, bs3);
    ws_kernel<<<(64 + 256 + 3) / 4, TPB, 0, stream>>>(W2, as2, ad2, 64, 256,
                                                      W3, as3, ad3, 256, 1024,
                                                      ws2, wd2, ws3, wd3);

    // ---- layer 1: gemm first (gather in 64-dim h1) ----
    mfma_gemm<128, 1, false><<<dim3(gR64, 1), TPB, 0, stream>>>(xb, Wt1, h1, nullptr, N, 64);
    sd_kernel<<<gW, TPB, 0, stream>>>(h1, as1, ad1, N, 64, sbuf, dbuf);
    alpha_kernel<<<gW, TPB, 0, stream>>>(sbuf, dbuf, srcg, offsets, N, ag);
    spmm_kernel<1, true><<<N, 64, 0, stream>>>(h1, ag, srcg, offsets, 64, b1, a1);

    // ---- layer 2: aggregate-then-gemm ----
    sd_kernel<<<gW, TPB, 0, stream>>>(a1, ws2, wd2, N, 64, sbuf, dbuf);
    alpha_kernel<<<gW, TPB, 0, stream>>>(sbuf, dbuf, srcg, offsets, N, ag);
    spmm_kernel<1, false><<<N, 64, 0, stream>>>(a1, ag, srcg, offsets, 64, nullptr, agg2);
    mfma_gemm<64, 2, true><<<dim3(gR128, 4), TPB, 0, stream>>>(agg2, Wt2, a2, b2, N, 256);

    // ---- layer 3: aggregate-then-gemm ----
    sd_kernel<<<gW, TPB, 0, stream>>>(a2, ws3, wd3, N, 256, sbuf, dbuf);
    alpha_kernel<<<gW, TPB, 0, stream>>>(sbuf, dbuf, srcg, offsets, N, ag);
    spmm_kernel<2, false><<<N, 128, 0, stream>>>(a2, ag, srcg, offsets, 256, nullptr, agg3);
    mfma_gemm<256, 2, true><<<dim3(gR128, 16), TPB, 0, stream>>>(agg3, Wt3, h3, b3, N, 1024);

    // ---- pool + head ----
    pool_kernel<<<256, TPB, 0, stream>>>(h3, N, pooled);
    head1a_kernel<<<dim3(4, 16), 128, 0, stream>>>(pooled, lw1, hpart);
    head1b_kernel<<<4, 128, 0, stream>>>(hpart, lb1, z1);
    head2_kernel<<<1, 64, 0, stream>>>(z1, lw2, lb2, out);
}